// Round 8
// baseline (81.291 us; speedup 1.0000x reference)
//
#include <hip/hip_runtime.h>
#include <hip/hip_fp16.h>

// SpMM: out = fp32( segment_sum( fp16(m)[col] * fp16(vals)[:,None], row ) )
// N=50000, NNZ=800000 (row sorted), D=256.
//
// Round 8: 2 edges per gather instruction + packed (col, half2(v,v)) edges.
//  - Lane l gathers 16 B (uint4) of row col[e0+2j+(l>=32)]: 32 lanes cover a
//    full 512 B fp16 row, so one dwordx4 instruction serves TWO edges.
//    16-deep batch = 32 edges -> ~1 gather window per row (avg deg 16).
//  - prep packs cv[e] = {col[e], half2(vals[e]) duplicated}: one dwordx2
//    stage load per 2 edges, no v_cvt in the hot loop.
//  - cross-half shfl_xor(32) reduce + interleaved float4 stores per row.
//  Fallbacks: round-7 path (mh+row_ptr only), then pure fp32.

#define D   256
#define D4  64   // D/4 floats
#define D8  32   // D/8
#define D16 32   // uint4 (16B) units per fp16 row: 512B/16B

__device__ __forceinline__ int lower_bound_dev(const int* __restrict__ a, int n, int key) {
    int lo = 0, hi = n;
    while (lo < hi) {
        int mid = (lo + hi) >> 1;
        if (a[mid] < key) lo = mid + 1;
        else hi = mid;
    }
    return lo;
}

// ---------------- prep: m -> fp16, cv pack, row -> row_ptr ----------------
__global__ __launch_bounds__(256) void prep_kernel(
        const float4* __restrict__ m4,
        const int* __restrict__ row,
        const int* __restrict__ col,
        const float* __restrict__ vals,
        int nnz, int n_rows,
        uint4* __restrict__ mh_vec,      // fp16 m, 8 halfs per uint4
        int2* __restrict__ cv,           // {col, half2(v,v)} per edge
        int* __restrict__ row_ptr) {
    const int tid = blockIdx.x * blockDim.x + threadIdx.x;
    const int nth = gridDim.x * blockDim.x;

    const int n_items = n_rows * D8;     // groups of 8 floats
    for (int i = tid; i < n_items; i += nth) {
        const float4 a = m4[2 * i];
        const float4 b = m4[2 * i + 1];
        union { __half h[8]; uint4 u; } pk;
        pk.h[0] = __float2half(a.x); pk.h[1] = __float2half(a.y);
        pk.h[2] = __float2half(a.z); pk.h[3] = __float2half(a.w);
        pk.h[4] = __float2half(b.x); pk.h[5] = __float2half(b.y);
        pk.h[6] = __float2half(b.z); pk.h[7] = __float2half(b.w);
        mh_vec[i] = pk.u;
    }

    for (int e = tid; e < nnz; e += nth) {
        const __half h = __float2half(vals[e]);
        const unsigned hu = (unsigned)__builtin_bit_cast(unsigned short, h);
        int2 t;
        t.x = col[e];
        t.y = (int)(hu | (hu << 16));    // half2(v, v)
        cv[e] = t;
    }

    for (int r = tid; r <= n_rows; r += nth) {
        row_ptr[r] = lower_bound_dev(row, nnz, r);
    }
}

// ---------------- main: 2-edges-per-gather fp16 SpMM ----------------
__global__ __launch_bounds__(256) void spmm_fp16x2_kernel(
        const uint4* __restrict__ mhv,   // 32 uint4 per row
        const int* __restrict__ row_ptr,
        const int2* __restrict__ cv,
        float4* __restrict__ out4,
        int n_rows) {
    const int wid   = threadIdx.x >> 6;
    const int lane  = threadIdx.x & 63;
    const int hlane = lane & 31;
    const int hi    = lane >> 5;         // 0: even edges, 1: odd edges
    const int r = blockIdx.x * 4 + wid;
    if (r >= n_rows) return;

    const int start = __builtin_amdgcn_readfirstlane(row_ptr[r]);
    const int end   = __builtin_amdgcn_readfirstlane(row_ptr[r + 1]);

    float a0 = 0.f, a1 = 0.f, a2 = 0.f, a3 = 0.f;
    float a4 = 0.f, a5 = 0.f, a6 = 0.f, a7 = 0.f;

    for (int e0 = start; e0 < end; e0 += 32) {
        int      c[16];
        unsigned hv[16];
        if (e0 + 32 <= end) {
            // full window: contiguous dwordx2 stage loads
            #pragma unroll
            for (int j = 0; j < 16; ++j) {
                const int2 t = cv[e0 + 2 * j + hi];
                c[j] = t.x; hv[j] = (unsigned)t.y;
            }
        } else {
            // partial window: clamp into [start,end), zero pad values
            const int last = end - 1;
            #pragma unroll
            for (int j = 0; j < 16; ++j) {
                const int e  = e0 + 2 * j + hi;
                const int ec = e < end ? e : last;
                const int2 t = cv[ec];
                c[j] = t.x;
                hv[j] = e < end ? (unsigned)t.y : 0u;
            }
        }

        // 16 independent dwordx4 gathers (each serves 2 edges wave-wide)
        uint4 g[16];
        #pragma unroll
        for (int j = 0; j < 16; ++j) {
            g[j] = mhv[(size_t)c[j] * D16 + hlane];
        }

        __builtin_amdgcn_sched_barrier(0);

        __half2 s0 = __float2half2_rn(0.f);
        __half2 s1 = __float2half2_rn(0.f);
        __half2 s2 = __float2half2_rn(0.f);
        __half2 s3 = __float2half2_rn(0.f);
        #pragma unroll
        for (int j = 0; j < 16; ++j) {
            const __half2 hva = __builtin_bit_cast(__half2, hv[j]);
            s0 = __hfma2(__builtin_bit_cast(__half2, g[j].x), hva, s0);
            s1 = __hfma2(__builtin_bit_cast(__half2, g[j].y), hva, s1);
            s2 = __hfma2(__builtin_bit_cast(__half2, g[j].z), hva, s2);
            s3 = __hfma2(__builtin_bit_cast(__half2, g[j].w), hva, s3);
        }
        float2 f;
        f = __half22float2(s0); a0 += f.x; a1 += f.y;
        f = __half22float2(s1); a2 += f.x; a3 += f.y;
        f = __half22float2(s2); a4 += f.x; a5 += f.y;
        f = __half22float2(s3); a6 += f.x; a7 += f.y;
    }

    // cross-half reduce: even-edge sums (lanes<32) + odd-edge sums (lanes>=32)
    a0 += __shfl_xor(a0, 32); a1 += __shfl_xor(a1, 32);
    a2 += __shfl_xor(a2, 32); a3 += __shfl_xor(a3, 32);
    a4 += __shfl_xor(a4, 32); a5 += __shfl_xor(a5, 32);
    a6 += __shfl_xor(a6, 32); a7 += __shfl_xor(a7, 32);

    // lane hlane owns d=[8*hlane, 8*hlane+8): two float4s; hi picks which
    const float4 o = hi ? make_float4(a4, a5, a6, a7)
                        : make_float4(a0, a1, a2, a3);
    out4[(size_t)r * D4 + hlane * 2 + hi] = o;
}

// ---------------- mid fallback: round-7 path (mh + row_ptr only) ----------------
__global__ __launch_bounds__(256) void spmm_fp16_kernel(
        const __half* __restrict__ mh,
        const int* __restrict__ row_ptr,
        const int* __restrict__ col,
        const float* __restrict__ vals,
        float4* __restrict__ out4,
        int n_rows) {
    const int wid  = threadIdx.x >> 6;
    const int lane = threadIdx.x & 63;
    const int r = blockIdx.x * 4 + wid;
    if (r >= n_rows) return;

    const int start = __builtin_amdgcn_readfirstlane(row_ptr[r]);
    const int end   = __builtin_amdgcn_readfirstlane(row_ptr[r + 1]);
    const uint2* __restrict__ mh2 = (const uint2*)mh;

    float a0 = 0.f, a1 = 0.f, a2 = 0.f, a3 = 0.f;
    for (int e0 = start; e0 < end; e0 += 16) {
        int   c[16];
        float v[16];
        if (e0 + 16 <= end) {
            #pragma unroll
            for (int j = 0; j < 16; ++j) { c[j] = col[e0 + j]; v[j] = vals[e0 + j]; }
        } else {
            const int last = end - 1;
            #pragma unroll
            for (int j = 0; j < 16; ++j) {
                const int e  = e0 + j;
                const int ec = e < end ? e : last;
                c[j] = col[ec];
                const float vv = vals[ec];
                v[j] = e < end ? vv : 0.f;
            }
        }
        uint2 g[16];
        #pragma unroll
        for (int j = 0; j < 16; ++j) g[j] = mh2[((size_t)c[j] << 6) + lane];
        __builtin_amdgcn_sched_barrier(0);
        __half2 s01a = __float2half2_rn(0.f), s23a = __float2half2_rn(0.f);
        __half2 s01b = __float2half2_rn(0.f), s23b = __float2half2_rn(0.f);
        #pragma unroll
        for (int j = 0; j < 16; j += 2) {
            const __half2 hva = __float2half2_rn(v[j]);
            s01a = __hfma2(__builtin_bit_cast(__half2, g[j].x), hva, s01a);
            s23a = __hfma2(__builtin_bit_cast(__half2, g[j].y), hva, s23a);
            const __half2 hvb = __float2half2_rn(v[j + 1]);
            s01b = __hfma2(__builtin_bit_cast(__half2, g[j + 1].x), hvb, s01b);
            s23b = __hfma2(__builtin_bit_cast(__half2, g[j + 1].y), hvb, s23b);
        }
        float2 f;
        f = __half22float2(s01a); a0 += f.x; a1 += f.y;
        f = __half22float2(s01b); a0 += f.x; a1 += f.y;
        f = __half22float2(s23a); a2 += f.x; a3 += f.y;
        f = __half22float2(s23b); a2 += f.x; a3 += f.y;
    }
    out4[(size_t)r * D4 + lane] = make_float4(a0, a1, a2, a3);
}

// ---------------- last fallback (fp32, no workspace) ----------------
__global__ __launch_bounds__(256) void spmm_fp32_kernel(
        const float4* __restrict__ m4,
        const int* __restrict__ row,
        const int* __restrict__ col,
        const float* __restrict__ vals,
        float4* __restrict__ out4,
        int n_rows, int nnz) {
    const int wid  = threadIdx.x >> 6;
    const int lane = threadIdx.x & 63;
    const int r = blockIdx.x * 4 + wid;
    if (r >= n_rows) return;

    const int start = lower_bound_dev(row, nnz, r);
    const int end   = lower_bound_dev(row, nnz, r + 1);

    float a0 = 0.f, a1 = 0.f, a2 = 0.f, a3 = 0.f;
    for (int e = start; e < end; ++e) {
        const int   c = col[e];
        const float v = vals[e];
        const float4 a = m4[(size_t)c * D4 + lane];
        const __half hv = __float2half(v);
        a0 += __half2float(__hmul(__float2half(a.x), hv));
        a1 += __half2float(__hmul(__float2half(a.y), hv));
        a2 += __half2float(__hmul(__float2half(a.z), hv));
        a3 += __half2float(__hmul(__float2half(a.w), hv));
    }
    out4[(size_t)r * D4 + lane] = make_float4(a0, a1, a2, a3);
}

extern "C" void kernel_launch(void* const* d_in, const int* in_sizes, int n_in,
                              void* d_out, int out_size, void* d_ws, size_t ws_size,
                              hipStream_t stream) {
    const float* m    = (const float*)d_in[0];
    const int*   row  = (const int*)d_in[1];
    const int*   col  = (const int*)d_in[2];
    const float* vals = (const float*)d_in[3];
    float*       out  = (float*)d_out;

    const int nnz    = in_sizes[1];
    const int n_rows = in_sizes[0] / D;   // 50000

    const size_t mh_bytes = (size_t)n_rows * D * sizeof(__half);      // 25.6 MB
    const size_t rp_bytes = (size_t)(n_rows + 1) * sizeof(int);       // 200 KB
    const size_t cv_bytes = (size_t)nnz * sizeof(int2);               // 6.4 MB
    const int blocks = (n_rows + 3) / 4;  // 4 rows (waves) per block

    if (ws_size >= mh_bytes + rp_bytes + cv_bytes) {
        __half* mh      = (__half*)d_ws;
        int*    row_ptr = (int*)((char*)d_ws + mh_bytes);
        int2*   cv      = (int2*)((char*)d_ws + mh_bytes + rp_bytes);

        const int n_items = n_rows * D8;              // 1.6M convert items
        const int pblocks = (n_items + 255) / 256;    // 6250 blocks
        prep_kernel<<<pblocks, 256, 0, stream>>>(
            (const float4*)m, row, col, vals, nnz, n_rows,
            (uint4*)mh, cv, row_ptr);

        spmm_fp16x2_kernel<<<blocks, 256, 0, stream>>>(
            (const uint4*)mh, row_ptr, cv, (float4*)out, n_rows);
    } else if (ws_size >= mh_bytes + rp_bytes) {
        __half* mh      = (__half*)d_ws;
        int*    row_ptr = (int*)((char*)d_ws + mh_bytes);

        const int n_items = n_rows * D8;
        const int pblocks = (n_items + 255) / 256;
        prep_kernel<<<pblocks, 256, 0, stream>>>(
            (const float4*)m, row, col, vals, 0 /*skip cv*/, n_rows,
            (uint4*)mh, nullptr, row_ptr);

        spmm_fp16_kernel<<<blocks, 256, 0, stream>>>(
            mh, row_ptr, col, vals, (float4*)out, n_rows);
    } else {
        spmm_fp32_kernel<<<blocks, 256, 0, stream>>>(
            (const float4*)m, row, col, vals, (float4*)out, n_rows, nnz);
    }
}

// Round 9
// 78.521 us; speedup vs baseline: 1.0353x; 1.0353x over previous
//
#include <hip/hip_runtime.h>
#include <hip/hip_fp16.h>

// SpMM: out = fp32( segment_sum( fp16(m)[col] * fp16(vals)[:,None], row ) )
// N=50000, NNZ=800000 (row sorted), D=256.
//
// Round 9: revert to the measured-best round-7 structure.
//  Evidence: r4/r6/r7/r8 all plateau at 3.5-3.9 TB/s of L2-miss traffic ->
//  random-512B-gather memory ceiling; r7's spmm (3.91 TB/s) is at it.
//  r8's 2-edges-per-gather added overhead (address divergence, padded
//  duplicate gathers, occupancy 60->45%) with zero benefit. Dropped.
//  Prep drops the cv pack (-12.8 MB traffic) and grid-strides 2048 blocks.
//
//  Kernel P: m fp32->fp16 into d_ws + row_ptr[N+1] via parallel binary search.
//  Kernel S: wave per row; lane owns 4 halfs (8 B); 16-deep gather windows
//    with sched_barrier(0) between issue and consume; fp16 pk_fma chains,
//    fp32 flush per window.

#define D   256
#define D4  64   // D/4 floats
#define D8  32   // D/8

__device__ __forceinline__ int lower_bound_dev(const int* __restrict__ a, int n, int key) {
    int lo = 0, hi = n;
    while (lo < hi) {
        int mid = (lo + hi) >> 1;
        if (a[mid] < key) lo = mid + 1;
        else hi = mid;
    }
    return lo;
}

// ---------------- prep: m -> fp16, row -> row_ptr ----------------
__global__ __launch_bounds__(256) void prep_kernel(
        const float4* __restrict__ m4,
        const int* __restrict__ row,
        int nnz, int n_rows,
        uint4* __restrict__ mh_vec,      // fp16 m, 8 halfs per uint4
        int* __restrict__ row_ptr) {
    const int tid = blockIdx.x * blockDim.x + threadIdx.x;
    const int nth = gridDim.x * blockDim.x;

    const int n_items = n_rows * D8;     // groups of 8 floats
    for (int i = tid; i < n_items; i += nth) {
        const float4 a = m4[2 * i];
        const float4 b = m4[2 * i + 1];
        union { __half h[8]; uint4 u; } pk;
        pk.h[0] = __float2half(a.x); pk.h[1] = __float2half(a.y);
        pk.h[2] = __float2half(a.z); pk.h[3] = __float2half(a.w);
        pk.h[4] = __float2half(b.x); pk.h[5] = __float2half(b.y);
        pk.h[6] = __float2half(b.z); pk.h[7] = __float2half(b.w);
        mh_vec[i] = pk.u;
    }

    for (int r = tid; r <= n_rows; r += nth) {
        row_ptr[r] = lower_bound_dev(row, nnz, r);
    }
}

// ---------------- main: fp16 gather SpMM, 16-wide MLP ----------------
__global__ __launch_bounds__(256) void spmm_fp16_kernel(
        const __half* __restrict__ mh,
        const int* __restrict__ row_ptr,
        const int* __restrict__ col,
        const float* __restrict__ vals,
        float4* __restrict__ out4,
        int n_rows) {
    const int wid  = threadIdx.x >> 6;
    const int lane = threadIdx.x & 63;
    const int r = blockIdx.x * 4 + wid;
    if (r >= n_rows) return;

    const int start = __builtin_amdgcn_readfirstlane(row_ptr[r]);
    const int end   = __builtin_amdgcn_readfirstlane(row_ptr[r + 1]);

    const uint2* __restrict__ mh2 = (const uint2*)mh;

    float a0 = 0.f, a1 = 0.f, a2 = 0.f, a3 = 0.f;

    for (int e0 = start; e0 < end; e0 += 16) {
        int   c[16];
        float v[16];
        if (e0 + 16 <= end) {
            // full window: contiguous unclamped loads
            #pragma unroll
            for (int j = 0; j < 16; ++j) {
                c[j] = col[e0 + j];
                v[j] = vals[e0 + j];
            }
        } else {
            // final partial window: clamp into [start,end), zero pad values
            const int last = end - 1;
            #pragma unroll
            for (int j = 0; j < 16; ++j) {
                const int e  = e0 + j;
                const int ec = e < end ? e : last;
                c[j] = col[ec];
                const float vv = vals[ec];
                v[j] = e < end ? vv : 0.f;
            }
        }

        // 16 independent gathers in flight (512 B per wave each)
        uint2 g[16];
        #pragma unroll
        for (int j = 0; j < 16; ++j) {
            g[j] = mh2[((size_t)c[j] << 6) + lane];
        }

        __builtin_amdgcn_sched_barrier(0);

        // fp16 packed-fma accumulation, two chains, fp32 flush per window
        __half2 s01a = __float2half2_rn(0.f);
        __half2 s23a = __float2half2_rn(0.f);
        __half2 s01b = __float2half2_rn(0.f);
        __half2 s23b = __float2half2_rn(0.f);
        #pragma unroll
        for (int j = 0; j < 16; j += 2) {
            const __half2 hva = __float2half2_rn(v[j]);
            s01a = __hfma2(__builtin_bit_cast(__half2, g[j].x), hva, s01a);
            s23a = __hfma2(__builtin_bit_cast(__half2, g[j].y), hva, s23a);
            const __half2 hvb = __float2half2_rn(v[j + 1]);
            s01b = __hfma2(__builtin_bit_cast(__half2, g[j + 1].x), hvb, s01b);
            s23b = __hfma2(__builtin_bit_cast(__half2, g[j + 1].y), hvb, s23b);
        }
        float2 f;
        f = __half22float2(s01a); a0 += f.x; a1 += f.y;
        f = __half22float2(s01b); a0 += f.x; a1 += f.y;
        f = __half22float2(s23a); a2 += f.x; a3 += f.y;
        f = __half22float2(s23b); a2 += f.x; a3 += f.y;
    }

    out4[(size_t)r * D4 + lane] = make_float4(a0, a1, a2, a3);
}

// ---------------- fallback (fp32 path, no workspace) ----------------
__global__ __launch_bounds__(256) void spmm_fp32_kernel(
        const float4* __restrict__ m4,
        const int* __restrict__ row,
        const int* __restrict__ col,
        const float* __restrict__ vals,
        float4* __restrict__ out4,
        int n_rows, int nnz) {
    const int wid  = threadIdx.x >> 6;
    const int lane = threadIdx.x & 63;
    const int r = blockIdx.x * 4 + wid;
    if (r >= n_rows) return;

    const int start = lower_bound_dev(row, nnz, r);
    const int end   = lower_bound_dev(row, nnz, r + 1);

    float a0 = 0.f, a1 = 0.f, a2 = 0.f, a3 = 0.f;
    for (int e = start; e < end; ++e) {
        const int   c = col[e];
        const float v = vals[e];
        const float4 a = m4[(size_t)c * D4 + lane];
        const __half hv = __float2half(v);
        a0 += __half2float(__hmul(__float2half(a.x), hv));
        a1 += __half2float(__hmul(__float2half(a.y), hv));
        a2 += __half2float(__hmul(__float2half(a.z), hv));
        a3 += __half2float(__hmul(__float2half(a.w), hv));
    }
    out4[(size_t)r * D4 + lane] = make_float4(a0, a1, a2, a3);
}

extern "C" void kernel_launch(void* const* d_in, const int* in_sizes, int n_in,
                              void* d_out, int out_size, void* d_ws, size_t ws_size,
                              hipStream_t stream) {
    const float* m    = (const float*)d_in[0];
    const int*   row  = (const int*)d_in[1];
    const int*   col  = (const int*)d_in[2];
    const float* vals = (const float*)d_in[3];
    float*       out  = (float*)d_out;

    const int nnz    = in_sizes[1];
    const int n_rows = in_sizes[0] / D;   // 50000

    const size_t mh_bytes = (size_t)n_rows * D * sizeof(__half);      // 25.6 MB
    const size_t rp_bytes = (size_t)(n_rows + 1) * sizeof(int);       // 200 KB
    const int blocks = (n_rows + 3) / 4;  // 4 rows (waves) per block

    if (ws_size >= mh_bytes + rp_bytes) {
        __half* mh      = (__half*)d_ws;
        int*    row_ptr = (int*)((char*)d_ws + mh_bytes);

        prep_kernel<<<2048, 256, 0, stream>>>(
            (const float4*)m, row, nnz, n_rows, (uint4*)mh, row_ptr);

        spmm_fp16_kernel<<<blocks, 256, 0, stream>>>(
            mh, row_ptr, col, vals, (float4*)out, n_rows);
    } else {
        spmm_fp32_kernel<<<blocks, 256, 0, stream>>>(
            (const float4*)m, row, col, vals, (float4*)out, n_rows, nnz);
    }
}